// Round 2
// baseline (1042.037 us; speedup 1.0000x reference)
//
#include <hip/hip_runtime.h>
#include <hip/hip_bf16.h>
#include <math.h>

using bf16 = __hip_bfloat16;

#define H_IMG 128
#define W_IMG 128
#define C_IN  200
#define NCLS  16
#define N0    16384
#define N1    4096
#define N2    1024
#define KNB   16
#define EPS   1e-5f
#define SLOPE 0.01f

__device__ __forceinline__ float ldf(const float* p, long i) { return p[i]; }
__device__ __forceinline__ float ldf(const bf16* p, long i) { return __bfloat162float(p[i]); }
__device__ __forceinline__ float leaky(float v) { return v >= 0.f ? v : SLOPE * v; }

// ---------- dtype detector: underlying fp32 read as bf16 stream shows wild exponents ----------
__global__ void detect_kernel(const unsigned short* __restrict__ x, int* __restrict__ flag) {
    if (threadIdx.x != 0 || blockIdx.x != 0) return;
    int cnt = 0;
    for (int i = 0; i < 4096; i++) {
        unsigned short e = (unsigned short)((x[i] >> 7) & 0xFF);
        if (e >= 0xC0) cnt++;   // |v| >= 2^65 or NaN/Inf — impossible for real bf16 activations
    }
    *flag = (cnt > 32) ? 1 : 0; // 1 => inputs are float32
}

// ---------------- BN stats ----------------
template <typename TX, typename TW>
__device__ __forceinline__ void bn_stats_body(const TX* __restrict__ X, int P, int C,
                                              const TW* __restrict__ g, const TW* __restrict__ b,
                                              float* __restrict__ alpha, float* __restrict__ beta) {
    int c = blockIdx.x;
    int t = threadIdx.x;
    float s = 0.f, s2 = 0.f;
    for (int p = t; p < P; p += 256) {
        float v = ldf(X, (long)p * C + c);
        s += v; s2 += v * v;
    }
    __shared__ float rs[256], rq[256];
    rs[t] = s; rq[t] = s2; __syncthreads();
    for (int k = 128; k > 0; k >>= 1) {
        if (t < k) { rs[t] += rs[t + k]; rq[t] += rq[t + k]; }
        __syncthreads();
    }
    if (t == 0) {
        float mu = rs[0] / (float)P;
        float var = rq[0] / (float)P - mu * mu;
        float a = rsqrtf(var + EPS) * ldf(g, c);
        alpha[c] = a;
        beta[c] = ldf(b, c) - mu * a;
    }
}

__global__ __launch_bounds__(256) void bn_stats_kernel(const void* X, int P, int C,
                                                       const void* g, const void* b,
                                                       float* alpha, float* beta,
                                                       const int* flag, int xraw) {
    if (*flag) bn_stats_body<float, float>((const float*)X, P, C, (const float*)g, (const float*)b, alpha, beta);
    else if (xraw) bn_stats_body<bf16, bf16>((const bf16*)X, P, C, (const bf16*)g, (const bf16*)b, alpha, beta);
    else bn_stats_body<float, bf16>((const float*)X, P, C, (const bf16*)g, (const bf16*)b, alpha, beta);
}

// ---------------- fold BN into weights ----------------
template <typename TW>
__device__ __forceinline__ void fold_body(const TW* __restrict__ W, const TW* __restrict__ bias,
                                          const float* __restrict__ alpha, const float* __restrict__ beta,
                                          float* __restrict__ Wf, float* __restrict__ Bf,
                                          int Ci, int Co, int omajor) {
    int j = blockIdx.x;
    int t = threadIdx.x;
    float acc = 0.f;
    for (int c = t; c < Ci; c += 256) {
        float w = omajor ? ldf(W, (long)j * Ci + c) : ldf(W, (long)c * Co + j);
        Wf[(long)c * Co + j] = w * alpha[c];
        acc += w * beta[c];
    }
    __shared__ float red[256];
    red[t] = acc; __syncthreads();
    for (int k = 128; k > 0; k >>= 1) { if (t < k) red[t] += red[t + k]; __syncthreads(); }
    if (t == 0) Bf[j] = ldf(bias, (long)j) + red[0];
}

__global__ __launch_bounds__(256) void fold_kernel(const void* W, const void* bias,
                                                   const float* alpha, const float* beta,
                                                   float* Wf, float* Bf, int Ci, int Co, int omajor,
                                                   const int* flag) {
    if (*flag) fold_body<float>((const float*)W, (const float*)bias, alpha, beta, Wf, Bf, Ci, Co, omajor);
    else fold_body<bf16>((const bf16*)W, (const bf16*)bias, alpha, beta, Wf, Bf, Ci, Co, omajor);
}

// ---------------- GEMM: Out[n,j] = act(sum_c In[n,c]*Wf[c,j] + Bf[j]) ----------------
template <typename T, int ACT>
__device__ __forceinline__ void gemm_body(const T* __restrict__ In, const float* __restrict__ Wf,
                                          const float* __restrict__ Bf, float* __restrict__ Out,
                                          int Ci, int Co) {
    int tid = blockIdx.x * 256 + threadIdx.x;
    int n = tid / Co;
    int j = tid - n * Co;
    const T* in = In + (long)n * Ci;
    float acc = Bf[j];
#pragma unroll 4
    for (int c = 0; c < Ci; c++) acc += ldf(in, (long)c) * Wf[(long)c * Co + j];
    if (ACT) acc = leaky(acc);
    Out[(long)n * Co + j] = acc;
}

// head GEMM: In is raw input
__global__ __launch_bounds__(256) void gemm_dyn_kernel(const void* In, const float* Wf, const float* Bf,
                                                       float* Out, int Ci, int Co, const int* flag) {
    if (*flag) gemm_body<float, 1>((const float*)In, Wf, Bf, Out, Ci, Co);
    else gemm_body<bf16, 1>((const bf16*)In, Wf, Bf, Out, Ci, Co);
}

template <int ACT>
__global__ __launch_bounds__(256) void gemm_f32_kernel(const float* In, const float* Wf, const float* Bf,
                                                       float* Out, int Ci, int Co) {
    gemm_body<float, ACT>(In, Wf, Bf, Out, Ci, Co);
}

// ---------------- depthwise 5x5 SAME + bias + leaky ----------------
template <typename TW>
__device__ __forceinline__ void dw_body(const float* __restrict__ In, const TW* __restrict__ dwp,
                                        const TW* __restrict__ dbp, float* __restrict__ Out) {
    int tid = blockIdx.x * 256 + threadIdx.x; // 16384*128
    int o = tid & 127;
    int p = tid >> 7;
    int h = p >> 7, w = p & 127;
    float wr[25];
#pragma unroll
    for (int i = 0; i < 25; i++) wr[i] = ldf(dwp, (long)o * 25 + i);
    float acc = ldf(dbp, (long)o);
#pragma unroll
    for (int dh = -2; dh <= 2; dh++) {
        int hh = h + dh;
        if ((unsigned)hh >= (unsigned)H_IMG) continue;
#pragma unroll
        for (int dv = -2; dv <= 2; dv++) {
            int ww = w + dv;
            if ((unsigned)ww >= (unsigned)W_IMG) continue;
            acc += In[(long)(((hh << 7) + ww) << 7) + o] * wr[(dh + 2) * 5 + (dv + 2)];
        }
    }
    Out[tid] = leaky(acc);
}

__global__ __launch_bounds__(256) void dw_kernel(const float* In, const void* dwp, const void* dbp,
                                                 float* Out, const int* flag) {
    if (*flag) dw_body<float>(In, (const float*)dwp, (const float*)dbp, Out);
    else dw_body<bf16>(In, (const bf16*)dwp, (const bf16*)dbp, Out);
}

// ---------------- avg-pool of 4 consecutive rows (Shat @ H) ----------------
__global__ __launch_bounds__(256) void pool4_kernel(const float* __restrict__ In, float* __restrict__ Out, int F) {
    int tid = blockIdx.x * 256 + threadIdx.x;
    int j = tid / F;
    int f = tid - j * F;
    const float* base = In + (long)(4 * j) * F + f;
    Out[tid] = 0.25f * (base[0] + base[F] + base[2 * F] + base[3 * F]);
}

// ---------------- GCN attention ----------------
__global__ __launch_bounds__(64) void attn_kernel(const float* __restrict__ th, const float* __restrict__ outm,
                                                  const int* __restrict__ nbr, float* __restrict__ dst, int co) {
    int n = blockIdx.x;
    int l = threadIdx.x; // 64
    float r0 = th[(long)n * 128 + l];
    float r1 = th[(long)n * 128 + 64 + l];
    int mk[KNB];
    float av[KNB];
#pragma unroll
    for (int k = 0; k < KNB; k++) {
        int m = nbr[n * KNB + k];
        mk[k] = m;
        float v = r0 * th[(long)m * 128 + l] + r1 * th[(long)m * 128 + 64 + l];
#pragma unroll
        for (int off = 32; off > 0; off >>= 1) v += __shfl_xor(v, off, 64);
        av[k] = 1.f / (1.f + expf(-v));
    }
    float amax = av[0];
#pragma unroll
    for (int k = 1; k < KNB; k++) amax = fmaxf(amax, av[k]);
    float den = 0.f;
#pragma unroll
    for (int k = 0; k < KNB; k++) { av[k] = expf(av[k] - amax); den += av[k]; }
    float rden = 1.f / den;
    if (l < co) {
        float acc = 0.f;
#pragma unroll
        for (int k = 0; k < KNB; k++) acc += av[k] * outm[(long)mk[k] * co + l];
        dst[(long)n * co + l] = leaky(acc * rden);
    }
}

// ---------------- concats ----------------
__global__ __launch_bounds__(256) void concat_hcat_kernel(const float* __restrict__ Hd, const float* __restrict__ enc1,
                                                          float* __restrict__ Hcat) {
    int tid = blockIdx.x * 256 + threadIdx.x; // 4096*96
    int n = tid / 96;
    int f = tid - n * 96;
    Hcat[tid] = (f < 32) ? Hd[(long)(n >> 2) * 32 + f] : enc1[(long)n * 64 + (f - 32)];
}

__global__ __launch_bounds__(256) void concat_g_kernel(const float* __restrict__ Hdec, const float* __restrict__ H0,
                                                       float* __restrict__ G) {
    int tid = blockIdx.x * 256 + threadIdx.x; // 16384*192
    int p = tid / 192;
    int f = tid - p * 192;
    G[tid] = (f < 64) ? Hdec[(long)(p >> 2) * 64 + f] : H0[(long)p * 128 + (f - 64)];
}

// ---------------- classifier ----------------
template <typename TW>
__device__ __forceinline__ void cls_body(const float* __restrict__ F, const TW* __restrict__ wsw,
                                         const TW* __restrict__ wb, TW* __restrict__ out) {
    int tid = blockIdx.x * 256 + threadIdx.x; // 16384*16
    int p = tid >> 4;
    int j = tid & 15;
    float acc = ldf(wb, (long)j);
#pragma unroll 4
    for (int c = 0; c < 128; c++) acc += F[(long)p * 128 + c] * ldf(wsw, (long)c * 16 + j);
    float m = acc;
#pragma unroll
    for (int s = 8; s > 0; s >>= 1) m = fmaxf(m, __shfl_xor(m, s, 16));
    float e = expf(acc - m);
    float d = e;
#pragma unroll
    for (int s = 8; s > 0; s >>= 1) d += __shfl_xor(d, s, 16);
    float r = e / d;
    if constexpr (sizeof(TW) == 2) out[tid] = __float2bfloat16(r);
    else out[tid] = r;
}

__global__ __launch_bounds__(256) void cls_kernel(const float* F, const void* wsw, const void* wb,
                                                  void* out, const int* flag) {
    if (*flag) cls_body<float>(F, (const float*)wsw, (const float*)wb, (float*)out);
    else cls_body<bf16>(F, (const bf16*)wsw, (const bf16*)wb, (bf16*)out);
}

// ================= host side =================
extern "C" void kernel_launch(void* const* d_in, const int* in_sizes, int n_in,
                              void* d_out, int out_size, void* d_ws, size_t ws_size,
                              hipStream_t stream) {
    bool dict = (in_sizes[1] > 1000000);
    int I_x, I_nbr_a, I_nbr_b, I_hg, I_ws, I_e0, I_e1, I_d0, I_tg;
    if (dict) {
        I_x = 0; I_nbr_a = 5; I_nbr_b = 6; I_hg = 7; I_e0 = 13; I_e1 = 19; I_d0 = 25; I_tg = 31; I_ws = 37;
    } else {
        I_x = 0; I_hg = 1; I_e0 = 7; I_e1 = 13; I_d0 = 19; I_tg = 25; I_ws = 31; I_nbr_a = 37; I_nbr_b = 38;
    }
    const void* x    = d_in[I_x];
    const int* nbr_a = (const int*)d_in[I_nbr_a];
    const int* nbr_b = (const int*)d_in[I_nbr_b];
    const void* hg   = d_in[I_hg + 0];
    const void* hb   = d_in[I_hg + 1];
    const void* hpw  = d_in[I_hg + 2];
    const void* hpb  = d_in[I_hg + 3];
    const void* hdw  = d_in[I_hg + 4];
    const void* hdb  = d_in[I_hg + 5];
    const void* e0_g = d_in[I_e0 + 0];
    const void* e0_b = d_in[I_e0 + 1];
    const void* e0_wt= d_in[I_e0 + 2];
    const void* e0_bt= d_in[I_e0 + 3];
    const void* e0_wo= d_in[I_e0 + 4];
    const void* e0_bo= d_in[I_e0 + 5];
    const void* e1_g = d_in[I_e1 + 0];
    const void* e1_b = d_in[I_e1 + 1];
    const void* e1_wt= d_in[I_e1 + 2];
    const void* e1_bt= d_in[I_e1 + 3];
    const void* e1_wo= d_in[I_e1 + 4];
    const void* e1_bo= d_in[I_e1 + 5];
    const void* d0_g = d_in[I_d0 + 0];
    const void* d0_b = d_in[I_d0 + 1];
    const void* d0_wt= d_in[I_d0 + 2];
    const void* d0_bt= d_in[I_d0 + 3];
    const void* d0_wo= d_in[I_d0 + 4];
    const void* d0_bo= d_in[I_d0 + 5];
    const void* tg   = d_in[I_tg + 0];
    const void* tb   = d_in[I_tg + 1];
    const void* tpw  = d_in[I_tg + 2];
    const void* tpb  = d_in[I_tg + 3];
    const void* tdw  = d_in[I_tg + 4];
    const void* tdb  = d_in[I_tg + 5];
    const void* wsw  = d_in[I_ws + 0];
    const void* wb   = d_in[I_ws + 1];

    float* W = (float*)d_ws;
    float* AB_a  = W + 0;
    float* AB_b  = W + 256;
    float* WF1   = W + 512;      // up to 128*200
    float* BF1   = W + 33280;
    float* WF2   = W + 33536;
    float* BF2   = W + 41728;
    int*   dflag = (int*)(W + 49152);
    float* R0    = W + 65536;          // 16384*192
    float* R1    = R0 + (long)N0*192;  // 16384*128
    float* H1b   = R1 + (long)N0*128;  // 4096*128
    float* THb   = H1b + (long)N1*128; // 4096*128
    float* OUTb  = THb + (long)N1*128; // 4096*64
    float* ENC1  = OUTb + (long)N1*64; // 4096*64
    float* H2b   = ENC1 + (long)N1*64; // 1024*64
    float* HDb   = H2b + (long)N2*64;  // 1024*32
    float* HCAT  = HDb + (long)N2*32;  // 4096*96
    float* HDEC  = HCAT + (long)N1*96; // 4096*64

    detect_kernel<<<1, 64, 0, stream>>>((const unsigned short*)x, dflag);

    // ---- head SSConv ----
    bn_stats_kernel<<<C_IN, 256, 0, stream>>>(x, N0, C_IN, hg, hb, AB_a, AB_b, dflag, 1);
    fold_kernel<<<128, 256, 0, stream>>>(hpw, hpb, AB_a, AB_b, WF1, BF1, C_IN, 128, 1, dflag);
    gemm_dyn_kernel<<<(N0 * 128) / 256, 256, 0, stream>>>(x, WF1, BF1, R0, C_IN, 128, dflag);
    dw_kernel<<<(N0 * 128) / 256, 256, 0, stream>>>(R0, hdw, hdb, R1, dflag); // R1 = enc0
    pool4_kernel<<<(N1 * 128) / 256, 256, 0, stream>>>(R1, H1b, 128);

    // ---- GCN e0: 128 -> 64 ----
    bn_stats_kernel<<<128, 256, 0, stream>>>(H1b, N1, 128, e0_g, e0_b, AB_a, AB_b, dflag, 0);
    fold_kernel<<<128, 256, 0, stream>>>(e0_wt, e0_bt, AB_a, AB_b, WF1, BF1, 128, 128, 0, dflag);
    fold_kernel<<<64, 256, 0, stream>>>(e0_wo, e0_bo, AB_a, AB_b, WF2, BF2, 128, 64, 0, dflag);
    gemm_f32_kernel<0><<<(N1 * 128) / 256, 256, 0, stream>>>(H1b, WF1, BF1, THb, 128, 128);
    gemm_f32_kernel<0><<<(N1 * 64) / 256, 256, 0, stream>>>(H1b, WF2, BF2, OUTb, 128, 64);
    attn_kernel<<<N1, 64, 0, stream>>>(THb, OUTb, nbr_a, ENC1, 64);
    pool4_kernel<<<(N2 * 64) / 256, 256, 0, stream>>>(ENC1, H2b, 64);

    // ---- GCN e1: 64 -> 32 ----
    bn_stats_kernel<<<64, 256, 0, stream>>>(H2b, N2, 64, e1_g, e1_b, AB_a, AB_b, dflag, 0);
    fold_kernel<<<128, 256, 0, stream>>>(e1_wt, e1_bt, AB_a, AB_b, WF1, BF1, 64, 128, 0, dflag);
    fold_kernel<<<32, 256, 0, stream>>>(e1_wo, e1_bo, AB_a, AB_b, WF2, BF2, 64, 32, 0, dflag);
    gemm_f32_kernel<0><<<(N2 * 128) / 256, 256, 0, stream>>>(H2b, WF1, BF1, THb, 64, 128);
    gemm_f32_kernel<0><<<(N2 * 32) / 256, 256, 0, stream>>>(H2b, WF2, BF2, OUTb, 64, 32);
    attn_kernel<<<N2, 64, 0, stream>>>(THb, OUTb, nbr_b, HDb, 32);

    // ---- decoder GCN d0 ----
    concat_hcat_kernel<<<(N1 * 96) / 256, 256, 0, stream>>>(HDb, ENC1, HCAT);
    bn_stats_kernel<<<96, 256, 0, stream>>>(HCAT, N1, 96, d0_g, d0_b, AB_a, AB_b, dflag, 0);
    fold_kernel<<<128, 256, 0, stream>>>(d0_wt, d0_bt, AB_a, AB_b, WF1, BF1, 96, 128, 0, dflag);
    fold_kernel<<<64, 256, 0, stream>>>(d0_wo, d0_bo, AB_a, AB_b, WF2, BF2, 96, 64, 0, dflag);
    gemm_f32_kernel<0><<<(N1 * 128) / 256, 256, 0, stream>>>(HCAT, WF1, BF1, THb, 96, 128);
    gemm_f32_kernel<0><<<(N1 * 64) / 256, 256, 0, stream>>>(HCAT, WF2, BF2, OUTb, 96, 64);
    attn_kernel<<<N1, 64, 0, stream>>>(THb, OUTb, nbr_a, HDEC, 64);

    // ---- tail ----
    concat_g_kernel<<<(N0 * 192) / 256, 256, 0, stream>>>(HDEC, R1, R0); // R0 = G
    bn_stats_kernel<<<192, 256, 0, stream>>>(R0, N0, 192, tg, tb, AB_a, AB_b, dflag, 0);
    fold_kernel<<<128, 256, 0, stream>>>(tpw, tpb, AB_a, AB_b, WF1, BF1, 192, 128, 1, dflag);
    gemm_f32_kernel<1><<<(N0 * 128) / 256, 256, 0, stream>>>(R0, WF1, BF1, R1, 192, 128); // R1 = T1
    dw_kernel<<<(N0 * 128) / 256, 256, 0, stream>>>(R1, tdw, tdb, R0, dflag); // R0 = F
    cls_kernel<<<(N0 * NCLS) / 256, 256, 0, stream>>>(R0, wsw, wb, d_out, dflag);
}